// Round 12
// baseline (43.120 us; speedup 1.0000x reference)
//
#include <hip/hip_runtime.h>
#include <math.h>

// DisCo (distance correlation) for N=8192, scalar output. FOUR dispatches.
// Algebra (validated R11, absmax 0.0):
//   r_i = avga_i - ha (ha = ga/2);  d' = |a_i-a_j| - r_j,  e' = |b_i-b_j| - s_j
//   Q'_i = sum_j w_j d' e'                     (ONE pairwise sum, 6 VALU/pair)
//   T_AB_i = Q'_i - s_i(P0a_i - Swr) - r_i(P0b_i - Sws) + r_i s_i W
//   S_AA   = 2W*Ma2 - 2Ma1^2 - 4N(Swr2 + ha*Swr) + 2W*Swr2 + 2Swr^2 (closed form)
//   K1 k_pass1   (512x4): partial row sums pa,pb[4][N] + dbl gpa/gpb[2048].
//   K2 k_mid     (32):    ha/hb; avg; rr=avga-ha, ss arrays; hs[2].
//   K3 k_pass2   (512x4): Q' only — streams a,b,w,rr,ss; Qp[4][N].
//   K4 k_tailfin (1x1024): 9 moments; per-row T_AB; num; closed-form dens;
//                 power branch; NaN/clamp. (~290KB reads on 1 CU, ~3us)
// R11->R12: merged tail+fin (5->4 dispatches; gaps measured ~4-5us each are
// now the largest cost). No atomics/fences (R4: per-block device fence =
// ~150us L2-writeback storm; grid.sync() has the same fence -> no coop fusion).
// Fixed-order reductions -> deterministic.

#define NN 8192
#define BLK 256
#define RPT 4
#define ROWS_PER_BLOCK 16
#define GRIDX 512
#define CSPLIT 4
#define SEGC 2048
#define ITERS 8
#define NBLK (GRIDX * CSPLIT)
#define MIDB 32
#define BLKF 1024
#define INV_N (1.0f / NN)
#define NSC 9   // 0:W 1:Ma1 2:Ma2 3:Mb1 4:Mb2 5:Swr 6:Sws 7:Swr2 8:Sws2

// ---------------------------------------------------------------- K1: pass 1
__device__ __forceinline__ void p1_elem(
    float aj, float bj, float wj,
    const float* __restrict__ ai, const float* __restrict__ bi,
    float* __restrict__ sa, float* __restrict__ sb) {
#pragma unroll
  for (int m = 0; m < RPT; ++m) {
    sa[m] = fmaf(fabsf(ai[m] - aj), wj, sa[m]);
    sb[m] = fmaf(fabsf(bi[m] - bj), wj, sb[m]);
  }
}

__global__ __launch_bounds__(BLK) void k_pass1(
    const float* __restrict__ a, const float* __restrict__ b,
    const float* __restrict__ w,
    float* __restrict__ pa, float* __restrict__ pb,
    double* __restrict__ gpa, double* __restrict__ gpb) {
  const int lane = threadIdx.x & 63;
  const int wv = threadIdx.x >> 6;
  const int i0 = blockIdx.x * ROWS_PER_BLOCK + wv * RPT;
  const int seg = blockIdx.y;

  float ai[RPT], bi[RPT], sa[RPT], sb[RPT];
#pragma unroll
  for (int m = 0; m < RPT; ++m) {
    ai[m] = a[i0 + m]; bi[m] = b[i0 + m];
    sa[m] = 0.f; sb[m] = 0.f;
  }

  const int jb = seg * SEGC;
  const float4* a4 = (const float4*)(a + jb) + lane;
  const float4* b4 = (const float4*)(b + jb) + lane;
  const float4* w4 = (const float4*)(w + jb) + lane;

  float4 A0 = a4[0], B0 = b4[0], W0 = w4[0];
#pragma unroll 1
  for (int k = 0; k < ITERS - 1; ++k) {
    const int nx = (k + 1) * 64;
    const float4 A1 = a4[nx], B1 = b4[nx], W1 = w4[nx];
    p1_elem(A0.x, B0.x, W0.x, ai, bi, sa, sb);
    p1_elem(A0.y, B0.y, W0.y, ai, bi, sa, sb);
    p1_elem(A0.z, B0.z, W0.z, ai, bi, sa, sb);
    p1_elem(A0.w, B0.w, W0.w, ai, bi, sa, sb);
    A0 = A1; B0 = B1; W0 = W1;
  }
  p1_elem(A0.x, B0.x, W0.x, ai, bi, sa, sb);
  p1_elem(A0.y, B0.y, W0.y, ai, bi, sa, sb);
  p1_elem(A0.z, B0.z, W0.z, ai, bi, sa, sb);
  p1_elem(A0.w, B0.w, W0.w, ai, bi, sa, sb);

#pragma unroll
  for (int off = 32; off >= 1; off >>= 1) {
#pragma unroll
    for (int m = 0; m < RPT; ++m) {
      sa[m] += __shfl_xor(sa[m], off);
      sb[m] += __shfl_xor(sb[m], off);
    }
  }

  __shared__ double gla[4], glb[4];
  if (lane == 0) {
#pragma unroll
    for (int m = 0; m < RPT; ++m) {
      pa[seg * NN + i0 + m] = sa[m];
      pb[seg * NN + i0 + m] = sb[m];
    }
    double da = 0.0, db = 0.0;
#pragma unroll
    for (int m = 0; m < RPT; ++m) {
      const double wi = (double)w[i0 + m];
      da += (double)sa[m] * wi;
      db += (double)sb[m] * wi;
    }
    gla[wv] = da; glb[wv] = db;
  }
  __syncthreads();
  if (threadIdx.x == 0) {
    const int bid = blockIdx.y * GRIDX + blockIdx.x;
    gpa[bid] = gla[0] + gla[1] + gla[2] + gla[3];
    gpb[bid] = glb[0] + glb[1] + glb[2] + glb[3];
  }
}

// --------------------------- K2: ha/hb; avg; rr/ss arrays; hs[2] (lean glue)
__global__ __launch_bounds__(BLK) void k_mid(
    const float* __restrict__ w,
    const float* __restrict__ pa, const float* __restrict__ pb,
    const double* __restrict__ gpa, const double* __restrict__ gpb,
    float* __restrict__ rr, float* __restrict__ ss,
    double* __restrict__ hs) {
  const int lane = threadIdx.x & 63;
  const int wv = threadIdx.x >> 6;

  __shared__ double gsum[2];
  if (wv < 2) {                 // wave0 -> ga partials, wave1 -> gb partials
    const double* g = wv ? gpb : gpa;
    double s = 0.0;
    for (int k = 0; k < NBLK / 64; ++k) s += g[lane + 64 * k];
#pragma unroll
    for (int off = 32; off >= 1; off >>= 1) s += __shfl_xor(s, off);
    if (lane == 0) gsum[wv] = s;
  }
  __syncthreads();
  const double n2 = (double)NN * (double)NN;
  const float ha = (float)(0.5 * gsum[0] / n2);   // ga/2
  const float hb = (float)(0.5 * gsum[1] / n2);
  if (blockIdx.x == 0 && threadIdx.x == 0) { hs[0] = (double)ha; hs[1] = (double)hb; }

  const int i = blockIdx.x * BLK + threadIdx.x;   // MIDB*BLK == NN
  const float av = (pa[i] + pa[NN + i] + pa[2 * NN + i] + pa[3 * NN + i]) * INV_N;
  const float bv = (pb[i] + pb[NN + i] + pb[2 * NN + i] + pb[3 * NN + i]) * INV_N;
  rr[i] = av - ha;
  ss[i] = bv - hb;
}

// ------------------- K3: pass 2 — single pairwise sum Q', 6 VALU per pair
__global__ __launch_bounds__(BLK) void k_pass2(
    const float* __restrict__ a, const float* __restrict__ b,
    const float* __restrict__ w,
    const float* __restrict__ rr, const float* __restrict__ ss,
    float* __restrict__ Qp) {
  const int lane = threadIdx.x & 63;
  const int wv = threadIdx.x >> 6;
  const int i0 = blockIdx.x * ROWS_PER_BLOCK + wv * RPT;
  const int seg = blockIdx.y;

  float ai[RPT], bi[RPT], q[RPT];
#pragma unroll
  for (int m = 0; m < RPT; ++m) {
    ai[m] = a[i0 + m]; bi[m] = b[i0 + m];
    q[m] = 0.f;
  }

  const int jb = seg * SEGC;
  const float4* a4 = (const float4*)(a + jb)  + lane;
  const float4* b4 = (const float4*)(b + jb)  + lane;
  const float4* w4 = (const float4*)(w + jb)  + lane;
  const float4* r4 = (const float4*)(rr + jb) + lane;
  const float4* s4 = (const float4*)(ss + jb) + lane;

#pragma unroll 1
  for (int k = 0; k < ITERS; ++k) {
    const int ix = k * 64;
    const float4 A = a4[ix], B = b4[ix], Wt = w4[ix], R = r4[ix], S = s4[ix];
#define P2E(e)                                            \
    {                                                     \
      _Pragma("unroll")                                   \
      for (int m = 0; m < RPT; ++m) {                     \
        const float dp = fabsf(ai[m] - A.e) - R.e;        \
        const float ep = fabsf(bi[m] - B.e) - S.e;        \
        q[m] = fmaf(Wt.e * dp, ep, q[m]);                 \
      }                                                   \
    }
    P2E(x) P2E(y) P2E(z) P2E(w)
#undef P2E
  }

#pragma unroll
  for (int off = 32; off >= 1; off >>= 1) {
#pragma unroll
    for (int m = 0; m < RPT; ++m) q[m] += __shfl_xor(q[m], off);
  }
  if (lane == 0) {
#pragma unroll
    for (int m = 0; m < RPT; ++m) Qp[seg * NN + i0 + m] = q[m];
  }
}

// --- K4: tail+fin — moments, per-row T_AB, num, closed-form dens, power branch
__global__ __launch_bounds__(BLKF) void k_tailfin(
    const float* __restrict__ a, const float* __restrict__ b,
    const float* __restrict__ w,
    const float* __restrict__ rr, const float* __restrict__ ss,
    const float* __restrict__ Qp, const double* __restrict__ hs,
    const int* __restrict__ powerPtr, float* __restrict__ out) {
  const int lane = threadIdx.x & 63;
  const int wvf = threadIdx.x >> 6;   // 16 waves
  const double n2 = (double)NN * (double)NN;
  const double ha = hs[0], hb = hs[1];

  // ---- phase B: 9 global moments
  double p[NSC];
#pragma unroll
  for (int t = 0; t < NSC; ++t) p[t] = 0.0;
  for (int k = 0; k < NN / BLKF; ++k) {
    const int i = threadIdx.x + k * BLKF;
    const double wi = (double)w[i];
    const double aiv = (double)a[i], biv = (double)b[i];
    const double ri = (double)rr[i], si = (double)ss[i];
    p[0] += wi;
    p[1] += wi * aiv;
    p[2] += wi * aiv * aiv;
    p[3] += wi * biv;
    p[4] += wi * biv * biv;
    p[5] += wi * ri;
    p[6] += wi * si;
    p[7] += wi * ri * ri;
    p[8] += wi * si * si;
  }
#pragma unroll
  for (int off = 32; off >= 1; off >>= 1) {
#pragma unroll
    for (int t = 0; t < NSC; ++t) p[t] += __shfl_xor(p[t], off);
  }
  __shared__ double lp[NSC][16];
  __shared__ double sc[NSC];
  if (lane == 0) {
#pragma unroll
    for (int t = 0; t < NSC; ++t) lp[t][wvf] = p[t];
  }
  __syncthreads();
  if (threadIdx.x < NSC) {
    double s = 0.0;
    for (int t = 0; t < 16; ++t) s += lp[threadIdx.x][t];
    sc[threadIdx.x] = s;
  }
  __syncthreads();
  const double W = sc[0], Swr = sc[5], Sws = sc[6];

  // ---- phase C: per-row T_AB + weighted abs reduce
  double ab = 0.0;
  for (int k = 0; k < NN / BLKF; ++k) {
    const int i = threadIdx.x + k * BLKF;
    const double Qi = (double)Qp[i] + Qp[NN + i] + Qp[2 * NN + i] + Qp[3 * NN + i];
    const double ri = (double)rr[i];
    const double si = (double)ss[i];
    const double wi = (double)w[i];
    const double P0a = (ri + ha) * (double)NN;   // N * avga_i
    const double P0b = (si + hb) * (double)NN;
    const double TAB = Qi - si * (P0a - Swr) - ri * (P0b - Sws) + ri * si * W;
    ab += fabs(TAB) * wi;
  }
#pragma unroll
  for (int off = 32; off >= 1; off >>= 1) ab += __shfl_xor(ab, off);
  __shared__ double l[16];
  if (lane == 0) l[wvf] = ab;
  __syncthreads();

  if (threadIdx.x == 0) {
    double sab = 0.0;
    for (int t = 0; t < 16; ++t) sab += l[t];
    const double Ma1 = sc[1], Ma2 = sc[2], Mb1 = sc[3], Mb2 = sc[4];
    const double Swr2 = sc[7], Sws2 = sc[8];

    const double S_AA = 2.0 * W * Ma2 - 2.0 * Ma1 * Ma1
                      - 4.0 * (double)NN * (Swr2 + ha * Swr)
                      + 2.0 * W * Swr2 + 2.0 * Swr * Swr;
    const double S_BB = 2.0 * W * Mb2 - 2.0 * Mb1 * Mb1
                      - 4.0 * (double)NN * (Sws2 + hb * Sws)
                      + 2.0 * W * Sws2 + 2.0 * Sws * Sws;

    const double num = sab / n2;
    const double mAA = S_AA / n2;
    const double mBB = S_BB / n2;
    const double den = fabs(mAA * mBB);
    const int pw = powerPtr[0];
    double d;
    if (pw == 1) {
      d = num / sqrt(den + 1e-12);
    } else if (pw == 2) {
      d = (num * num) / (den + 1e-12);
    } else {
      d = pow(num / sqrt(mAA * mBB) + 1e-12, (double)pw);
    }
    if (isnan(d)) d = 0.0;
    if (d < 0.0) d = 0.0;
    out[0] = (float)d;
  }
}

// -------------------------------------------------------------------- launcher
extern "C" void kernel_launch(void* const* d_in, const int* in_sizes, int n_in,
                              void* d_out, int out_size, void* d_ws, size_t ws_size,
                              hipStream_t stream) {
  const float* a = (const float*)d_in[0];
  const float* b = (const float*)d_in[1];
  const float* w = (const float*)d_in[2];
  const int* power = (const int*)d_in[3];
  float* out = (float*)d_out;

  double* dws = (double*)d_ws;           // 8B-aligned base
  double* gpa = dws;                     // [2048]
  double* gpb = gpa + NBLK;              // [2048]
  double* hs  = gpb + NBLK;              // [2]
  float* fp   = (float*)(hs + 2);
  float* pa   = fp;                      // [4N]
  float* pb   = pa + 4 * NN;             // [4N]
  float* Qp   = pb + 4 * NN;             // [4N]
  float* rr   = Qp + 4 * NN;             // [N]
  float* ss   = rr + NN;                 // [N]

  const dim3 grid(GRIDX, CSPLIT);
  k_pass1<<<grid, BLK, 0, stream>>>(a, b, w, pa, pb, gpa, gpb);
  k_mid<<<MIDB, BLK, 0, stream>>>(w, pa, pb, gpa, gpb, rr, ss, hs);
  k_pass2<<<grid, BLK, 0, stream>>>(a, b, w, rr, ss, Qp);
  k_tailfin<<<1, BLKF, 0, stream>>>(a, b, w, rr, ss, Qp, hs, power, out);
}

// Round 13
// 39.479 us; speedup vs baseline: 1.0922x; 1.0922x over previous
//
#include <hip/hip_runtime.h>
#include <math.h>

// DisCo (distance correlation) for N=8192, scalar output. FOUR dispatches.
// Algebra (validated R11, absmax 0.0):
//   r_i = avga_i - ha (ha = ga/2);  d' = |a_i-a_j| - r_j,  e' = |b_i-b_j| - s_j
//   Q'_i = sum_j w_j d' e'                    (ONE pairwise sum, 6 VALU/pair)
//   T_AB_i = Q'_i - s_i(P0a_i - Swr) - r_i(P0b_i - Sws) + r_i s_i W
//   S_AA   = 2W*Ma2 - 2Ma1^2 - 4N(Swr2 + ha*Swr) + 2W*Swr2 + 2Swr^2 (closed)
// R12 lesson: 1-block serial merges lose (gap ~3us < 1-CU O(N) work ~6-8us).
// R13: fold the tail into pass2 WIDE: each pass2 block owns 4 COMPLETE rows
// (4 waves x 4 col-segments), LDS-combines Q', finishes T_AB in-block using
// W/Swr/Sws reduced from k_mid's 32 partials by a cheap wave prologue
// (96 broadcast loads — NOT R6's 4096-load mistake), writes w|T_AB| partial.
//   K1 k_pass1 (512x4): R11-exact partial row sums pa,pb + dbl gpa/gpb[2048].
//   K2 k_mid   (32):    ha/hb; rr/ss arrays; 9 moment partials scal[9][32].
//   K3 k_pass2 (2048):  full-row Q' + in-block T_AB -> fAB[2048] (double).
//   K4 k_fin   (1x256): reduce fAB + scal; closed-form dens; power; clamp.
// No atomics/fences (R4). Fixed-order reductions -> deterministic.

#define NN 8192
#define BLK 256
#define RPT 4
#define ROWS_PER_BLOCK 16
#define GRIDX 512
#define CSPLIT 4
#define SEGC 2048
#define ITERS 8
#define NBLK (GRIDX * CSPLIT)
#define MIDB 32
#define G2BLK 2048                // pass2 blocks (4 full rows each)
#define INV_N (1.0f / NN)
#define NSC 9   // 0:W 1:Ma1 2:Ma2 3:Mb1 4:Mb2 5:Swr 6:Sws 7:Swr2 8:Sws2

// ---------------------------------------------------------------- K1: pass 1
__device__ __forceinline__ void p1_elem(
    float aj, float bj, float wj,
    const float* __restrict__ ai, const float* __restrict__ bi,
    float* __restrict__ sa, float* __restrict__ sb) {
#pragma unroll
  for (int m = 0; m < RPT; ++m) {
    sa[m] = fmaf(fabsf(ai[m] - aj), wj, sa[m]);
    sb[m] = fmaf(fabsf(bi[m] - bj), wj, sb[m]);
  }
}

__global__ __launch_bounds__(BLK) void k_pass1(
    const float* __restrict__ a, const float* __restrict__ b,
    const float* __restrict__ w,
    float* __restrict__ pa, float* __restrict__ pb,
    double* __restrict__ gpa, double* __restrict__ gpb) {
  const int lane = threadIdx.x & 63;
  const int wv = threadIdx.x >> 6;
  const int i0 = blockIdx.x * ROWS_PER_BLOCK + wv * RPT;
  const int seg = blockIdx.y;

  float ai[RPT], bi[RPT], sa[RPT], sb[RPT];
#pragma unroll
  for (int m = 0; m < RPT; ++m) {
    ai[m] = a[i0 + m]; bi[m] = b[i0 + m];
    sa[m] = 0.f; sb[m] = 0.f;
  }

  const int jb = seg * SEGC;
  const float4* a4 = (const float4*)(a + jb) + lane;
  const float4* b4 = (const float4*)(b + jb) + lane;
  const float4* w4 = (const float4*)(w + jb) + lane;

  float4 A0 = a4[0], B0 = b4[0], W0 = w4[0];
#pragma unroll 1
  for (int k = 0; k < ITERS - 1; ++k) {
    const int nx = (k + 1) * 64;
    const float4 A1 = a4[nx], B1 = b4[nx], W1 = w4[nx];
    p1_elem(A0.x, B0.x, W0.x, ai, bi, sa, sb);
    p1_elem(A0.y, B0.y, W0.y, ai, bi, sa, sb);
    p1_elem(A0.z, B0.z, W0.z, ai, bi, sa, sb);
    p1_elem(A0.w, B0.w, W0.w, ai, bi, sa, sb);
    A0 = A1; B0 = B1; W0 = W1;
  }
  p1_elem(A0.x, B0.x, W0.x, ai, bi, sa, sb);
  p1_elem(A0.y, B0.y, W0.y, ai, bi, sa, sb);
  p1_elem(A0.z, B0.z, W0.z, ai, bi, sa, sb);
  p1_elem(A0.w, B0.w, W0.w, ai, bi, sa, sb);

#pragma unroll
  for (int off = 32; off >= 1; off >>= 1) {
#pragma unroll
    for (int m = 0; m < RPT; ++m) {
      sa[m] += __shfl_xor(sa[m], off);
      sb[m] += __shfl_xor(sb[m], off);
    }
  }

  __shared__ double gla[4], glb[4];
  if (lane == 0) {
#pragma unroll
    for (int m = 0; m < RPT; ++m) {
      pa[seg * NN + i0 + m] = sa[m];
      pb[seg * NN + i0 + m] = sb[m];
    }
    double da = 0.0, db = 0.0;
#pragma unroll
    for (int m = 0; m < RPT; ++m) {
      const double wi = (double)w[i0 + m];
      da += (double)sa[m] * wi;
      db += (double)sb[m] * wi;
    }
    gla[wv] = da; glb[wv] = db;
  }
  __syncthreads();
  if (threadIdx.x == 0) {
    const int bid = blockIdx.y * GRIDX + blockIdx.x;
    gpa[bid] = gla[0] + gla[1] + gla[2] + gla[3];
    gpb[bid] = glb[0] + glb[1] + glb[2] + glb[3];
  }
}

// ---------------- K2: ha/hb; rr/ss arrays; 9 moment partials; hs[2] scalars
__global__ __launch_bounds__(BLK) void k_mid(
    const float* __restrict__ a, const float* __restrict__ b,
    const float* __restrict__ w,
    const float* __restrict__ pa, const float* __restrict__ pb,
    const double* __restrict__ gpa, const double* __restrict__ gpb,
    float* __restrict__ rr, float* __restrict__ ss,
    double* __restrict__ scal, double* __restrict__ hs) {
  const int lane = threadIdx.x & 63;
  const int wv = threadIdx.x >> 6;

  __shared__ double gsum[2];
  if (wv < 2) {                 // wave0 -> ga partials, wave1 -> gb partials
    const double* g = wv ? gpb : gpa;
    double s = 0.0;
    for (int k = 0; k < NBLK / 64; ++k) s += g[lane + 64 * k];
#pragma unroll
    for (int off = 32; off >= 1; off >>= 1) s += __shfl_xor(s, off);
    if (lane == 0) gsum[wv] = s;
  }
  __syncthreads();
  const double n2 = (double)NN * (double)NN;
  const float ha = (float)(0.5 * gsum[0] / n2);   // ga/2
  const float hb = (float)(0.5 * gsum[1] / n2);
  if (blockIdx.x == 0 && threadIdx.x == 0) { hs[0] = (double)ha; hs[1] = (double)hb; }

  const int i = blockIdx.x * BLK + threadIdx.x;   // MIDB*BLK == NN
  const float av = (pa[i] + pa[NN + i] + pa[2 * NN + i] + pa[3 * NN + i]) * INV_N;
  const float bv = (pb[i] + pb[NN + i] + pb[2 * NN + i] + pb[3 * NN + i]) * INV_N;
  const float ri = av - ha;
  const float si = bv - hb;
  const float wi = w[i], aiv = a[i], biv = b[i];
  rr[i] = ri;  ss[i] = si;

  double p[NSC];
  p[0] = (double)wi;
  p[1] = (double)wi * aiv;
  p[2] = (double)wi * aiv * aiv;
  p[3] = (double)wi * biv;
  p[4] = (double)wi * biv * biv;
  p[5] = (double)wi * ri;
  p[6] = (double)wi * si;
  p[7] = (double)wi * ri * ri;
  p[8] = (double)wi * si * si;
#pragma unroll
  for (int off = 32; off >= 1; off >>= 1) {
#pragma unroll
    for (int t = 0; t < NSC; ++t) p[t] += __shfl_xor(p[t], off);
  }
  __shared__ double lp[NSC][4];
  if (lane == 0) {
#pragma unroll
    for (int t = 0; t < NSC; ++t) lp[t][wv] = p[t];
  }
  __syncthreads();
  if (threadIdx.x == 0) {
#pragma unroll
    for (int t = 0; t < NSC; ++t)
      scal[t * MIDB + blockIdx.x] = lp[t][0] + lp[t][1] + lp[t][2] + lp[t][3];
  }
}

// ---- K3: pass 2 — full rows per block; Q' sweep + in-block T_AB finish
__global__ __launch_bounds__(BLK) void k_pass2(
    const float* __restrict__ a, const float* __restrict__ b,
    const float* __restrict__ w,
    const float* __restrict__ rr, const float* __restrict__ ss,
    const double* __restrict__ scal, const double* __restrict__ hs,
    double* __restrict__ fAB) {
  const int lane = threadIdx.x & 63;
  const int wv = threadIdx.x >> 6;
  const int i0 = blockIdx.x * RPT;            // 4 complete rows per block

  // wave prologue: W, Swr, Sws from k_mid's 32 partials (broadcast loads,
  // 5-step 32-lane butterfly; lanes 0-31 / 32-63 read identical data)
  double Wd   = scal[0 * MIDB + (lane & 31)];
  double Swrd = scal[5 * MIDB + (lane & 31)];
  double Swsd = scal[6 * MIDB + (lane & 31)];
#pragma unroll
  for (int off = 16; off >= 1; off >>= 1) {
    Wd   += __shfl_xor(Wd, off);
    Swrd += __shfl_xor(Swrd, off);
    Swsd += __shfl_xor(Swsd, off);
  }

  float ai[RPT], bi[RPT], q[RPT];
#pragma unroll
  for (int m = 0; m < RPT; ++m) {
    ai[m] = a[i0 + m]; bi[m] = b[i0 + m];
    q[m] = 0.f;
  }

  const int jb = wv * SEGC;                   // wave -> column segment
  const float4* a4 = (const float4*)(a + jb)  + lane;
  const float4* b4 = (const float4*)(b + jb)  + lane;
  const float4* w4 = (const float4*)(w + jb)  + lane;
  const float4* r4 = (const float4*)(rr + jb) + lane;
  const float4* s4 = (const float4*)(ss + jb) + lane;

#pragma unroll 1
  for (int k = 0; k < ITERS; ++k) {
    const int ix = k * 64;
    const float4 A = a4[ix], B = b4[ix], Wt = w4[ix], R = r4[ix], S = s4[ix];
#define P2E(e)                                            \
    {                                                     \
      _Pragma("unroll")                                   \
      for (int m = 0; m < RPT; ++m) {                     \
        const float dp = fabsf(ai[m] - A.e) - R.e;        \
        const float ep = fabsf(bi[m] - B.e) - S.e;        \
        q[m] = fmaf(Wt.e * dp, ep, q[m]);                 \
      }                                                   \
    }
    P2E(x) P2E(y) P2E(z) P2E(w)
#undef P2E
  }

#pragma unroll
  for (int off = 32; off >= 1; off >>= 1) {
#pragma unroll
    for (int m = 0; m < RPT; ++m) q[m] += __shfl_xor(q[m], off);
  }

  __shared__ float lq[CSPLIT][RPT];
  __shared__ double lab[RPT];
  if (lane == 0) {
#pragma unroll
    for (int m = 0; m < RPT; ++m) lq[wv][m] = q[m];
  }
  __syncthreads();
  if (threadIdx.x < RPT) {                    // lanes 0-3 of wave 0 hold Wd etc.
    const int m = threadIdx.x;
    const double Qi = (double)lq[0][m] + lq[1][m] + lq[2][m] + lq[3][m];
    const double ha = hs[0], hb = hs[1];
    const double ri = (double)rr[i0 + m];
    const double si = (double)ss[i0 + m];
    const double wi = (double)w[i0 + m];
    const double P0a = (ri + ha) * (double)NN;   // N * avga_i
    const double P0b = (si + hb) * (double)NN;
    const double TAB = Qi - si * (P0a - Swrd) - ri * (P0b - Swsd) + ri * si * Wd;
    lab[m] = fabs(TAB) * wi;
  }
  __syncthreads();
  if (threadIdx.x == 0)
    fAB[blockIdx.x] = lab[0] + lab[1] + lab[2] + lab[3];
}

// ---------- K4: finalize — reduce fAB[2048]+scal; closed-form dens; power
__global__ __launch_bounds__(BLK) void k_fin(
    const double* __restrict__ fAB, const double* __restrict__ scal,
    const double* __restrict__ hs, const int* __restrict__ powerPtr,
    float* __restrict__ out) {
  const int lane = threadIdx.x & 63;
  const int wv = threadIdx.x >> 6;

  double ab = 0.0;
#pragma unroll
  for (int k = 0; k < G2BLK / BLK; ++k) ab += fAB[threadIdx.x + k * BLK];
#pragma unroll
  for (int off = 32; off >= 1; off >>= 1) ab += __shfl_xor(ab, off);
  __shared__ double l[4];
  __shared__ double sc[NSC];
  if (lane == 0) l[wv] = ab;
  if (threadIdx.x < NSC) {
    double s = 0.0;
    for (int k = 0; k < MIDB; ++k) s += scal[threadIdx.x * MIDB + k];
    sc[threadIdx.x] = s;
  }
  __syncthreads();

  if (threadIdx.x == 0) {
    const double n2 = (double)NN * (double)NN;
    const double sab = l[0] + l[1] + l[2] + l[3];
    const double W = sc[0], Ma1 = sc[1], Ma2 = sc[2], Mb1 = sc[3], Mb2 = sc[4];
    const double Swr = sc[5], Sws = sc[6], Swr2 = sc[7], Sws2 = sc[8];
    const double ha = hs[0], hb = hs[1];

    const double S_AA = 2.0 * W * Ma2 - 2.0 * Ma1 * Ma1
                      - 4.0 * (double)NN * (Swr2 + ha * Swr)
                      + 2.0 * W * Swr2 + 2.0 * Swr * Swr;
    const double S_BB = 2.0 * W * Mb2 - 2.0 * Mb1 * Mb1
                      - 4.0 * (double)NN * (Sws2 + hb * Sws)
                      + 2.0 * W * Sws2 + 2.0 * Sws * Sws;

    const double num = sab / n2;
    const double mAA = S_AA / n2;
    const double mBB = S_BB / n2;
    const double den = fabs(mAA * mBB);
    const int p = powerPtr[0];
    double d;
    if (p == 1) {
      d = num / sqrt(den + 1e-12);
    } else if (p == 2) {
      d = (num * num) / (den + 1e-12);
    } else {
      d = pow(num / sqrt(mAA * mBB) + 1e-12, (double)p);
    }
    if (isnan(d)) d = 0.0;
    if (d < 0.0) d = 0.0;
    out[0] = (float)d;
  }
}

// -------------------------------------------------------------------- launcher
extern "C" void kernel_launch(void* const* d_in, const int* in_sizes, int n_in,
                              void* d_out, int out_size, void* d_ws, size_t ws_size,
                              hipStream_t stream) {
  const float* a = (const float*)d_in[0];
  const float* b = (const float*)d_in[1];
  const float* w = (const float*)d_in[2];
  const int* power = (const int*)d_in[3];
  float* out = (float*)d_out;

  double* dws = (double*)d_ws;           // 8B-aligned base
  double* gpa  = dws;                    // [2048]
  double* gpb  = gpa + NBLK;             // [2048]
  double* scal = gpb + NBLK;             // [9*32]
  double* hs   = scal + NSC * MIDB;      // [2]
  double* fAB  = hs + 2;                 // [2048]
  float* fp    = (float*)(fAB + G2BLK);
  float* pa    = fp;                     // [4N]
  float* pb    = pa + 4 * NN;            // [4N]
  float* rr    = pb + 4 * NN;            // [N]
  float* ss    = rr + NN;                // [N]

  const dim3 grid(GRIDX, CSPLIT);
  k_pass1<<<grid, BLK, 0, stream>>>(a, b, w, pa, pb, gpa, gpb);
  k_mid<<<MIDB, BLK, 0, stream>>>(a, b, w, pa, pb, gpa, gpb, rr, ss, scal, hs);
  k_pass2<<<G2BLK, BLK, 0, stream>>>(a, b, w, rr, ss, scal, hs, fAB);
  k_fin<<<1, BLK, 0, stream>>>(fAB, scal, hs, power, out);
}